// Round 6
// baseline (347.523 us; speedup 1.0000x reference)
//
#include <hip/hip_runtime.h>
#include <cmath>

#define DIMM 1024
#define NHEADS 16
#define NKV 4
#define HD 64
#define SEQ 1024
#define BSZ 8
#define ROWS (BSZ * SEQ)   // 8192

typedef unsigned short u16;
typedef __attribute__((ext_vector_type(8))) short bf16x8;
typedef __attribute__((ext_vector_type(4))) float f32x4;
typedef __attribute__((ext_vector_type(4))) unsigned short u16x4;

static __device__ __forceinline__ u16 f2bf(float f) {
    union { float f; unsigned u; } v; v.f = f;
    unsigned r = v.u + 0x7FFFu + ((v.u >> 16) & 1u);
    return (u16)(r >> 16);
}

// async global->LDS, 16B per lane; dst must be wave-uniform base (HW adds lane*16)
static __device__ __forceinline__ void gload16(const u16* g, u16* l) {
    __builtin_amdgcn_global_load_lds(
        (const __attribute__((address_space(1))) unsigned int*)g,
        (__attribute__((address_space(3))) unsigned int*)l, 16, 0, 0);
}

// ---------------- weight abs-mean partial reduce ----------------
__global__ __launch_bounds__(256) void k_absmean(const float* __restrict__ w, int n,
                                                 float* __restrict__ partial) {
    float s = 0.f;
    for (int i = blockIdx.x * 256 + threadIdx.x; i < n; i += 64 * 256) s += fabsf(w[i]);
    #pragma unroll
    for (int off = 32; off; off >>= 1) s += __shfl_xor(s, off);
    __shared__ float red[4];
    if ((threadIdx.x & 63) == 0) red[threadIdx.x >> 6] = s;
    __syncthreads();
    if (threadIdx.x == 0) partial[blockIdx.x] = red[0] + red[1] + red[2] + red[3];
}

// ---------------- alpha = max(mean|w|, eps) ----------------
__global__ void k_alpha(const float* __restrict__ partial, float* __restrict__ alpha) {
    int i = threadIdx.x;
    if (i < 4) {
        const int ns[4] = {1048576, 262144, 262144, 1048576};
        float s = 0.f;
        for (int j = 0; j < 64; ++j) s += partial[i * 64 + j];
        alpha[i] = fmaxf(s / (float)ns[i], 1e-8f);
    }
}

// ---------------- ternarize -> bf16 (values {-1,0,1}, exact) ----------------
__global__ __launch_bounds__(256) void k_tern(const float* __restrict__ w,
                                              const float* __restrict__ alpha, int ai,
                                              u16* __restrict__ wt, int n4) {
    float a = alpha[ai];
    for (int i = blockIdx.x * blockDim.x + threadIdx.x; i < n4; i += gridDim.x * blockDim.x) {
        float4 v = *reinterpret_cast<const float4*>(&w[i * 4]);
        u16x4 o;
        o.x = f2bf(rintf(fminf(fmaxf(v.x / a, -1.f), 1.f)));
        o.y = f2bf(rintf(fminf(fmaxf(v.y / a, -1.f), 1.f)));
        o.z = f2bf(rintf(fminf(fmaxf(v.z / a, -1.f), 1.f)));
        o.w = f2bf(rintf(fminf(fmaxf(v.w / a, -1.f), 1.f)));
        *reinterpret_cast<u16x4*>(&wt[i * 4]) = o;
    }
}

// ---------------- per-row activation quantization -> bf16 ints ----------------
__global__ __launch_bounds__(256) void k_quant(const float* __restrict__ X,
                                               u16* __restrict__ Xq, float* __restrict__ g) {
    int row = blockIdx.x;
    const float* xr = X + (size_t)row * DIMM;
    float4 v = *reinterpret_cast<const float4*>(&xr[threadIdx.x * 4]);
    float mv = fmaxf(fmaxf(fabsf(v.x), fabsf(v.y)), fmaxf(fabsf(v.z), fabsf(v.w)));
    #pragma unroll
    for (int off = 32; off; off >>= 1) mv = fmaxf(mv, __shfl_xor(mv, off));
    __shared__ float red[4];
    if ((threadIdx.x & 63) == 0) red[threadIdx.x >> 6] = mv;
    __syncthreads();
    mv = fmaxf(fmaxf(red[0], red[1]), fmaxf(red[2], red[3]));
    float gamma = fmaxf(mv, 1e-8f) / 127.0f;
    u16x4 o;
    o.x = f2bf(rintf(fminf(fmaxf(v.x / gamma, -128.f), 127.f)));
    o.y = f2bf(rintf(fminf(fmaxf(v.y / gamma, -128.f), 127.f)));
    o.z = f2bf(rintf(fminf(fmaxf(v.z / gamma, -128.f), 127.f)));
    o.w = f2bf(rintf(fminf(fmaxf(v.w / gamma, -128.f), 127.f)));
    *reinterpret_cast<u16x4*>(&Xq[(size_t)row * DIMM + threadIdx.x * 4]) = o;
    if (threadIdx.x == 0) g[row] = gamma;
}

// ---------------- bf16 MFMA GEMM (m97 structure + XOR-swizzled LDS) ----------------
// mode >= 0: C *= gamma[row]*alpha[mode].  mode < 0: fused QKV (cols 0..1023 -> alpha[0],
// 1024..1279 -> alpha[1], 1280..1535 -> alpha[2]).
__global__ __launch_bounds__(256) void k_gemm_mfma(const u16* __restrict__ A,
                                                   const u16* __restrict__ B,
                                                   const float* __restrict__ gamma,
                                                   const float* __restrict__ alpha_p, int mode,
                                                   float* __restrict__ C, int cols) {
    __shared__ u16 As[128 * 64];
    __shared__ u16 Bs[128 * 64];
    const int K = DIMM;
    int tid = threadIdx.x;
    int w = tid >> 6, lane = tid & 63;
    int lr = lane & 15, lg = lane >> 4;
    int lr7 = lr & 7;
    int wm = w >> 1, wn = w & 1;
    int row0 = blockIdx.y * 128, col0 = blockIdx.x * 128;

    f32x4 acc[4][4];
    #pragma unroll
    for (int mf = 0; mf < 4; ++mf)
        #pragma unroll
        for (int nf = 0; nf < 4; ++nf) acc[mf][nf] = (f32x4){0.f, 0.f, 0.f, 0.f};

    int srow = w * 32 + (lane >> 3);
    int scol = 8 * ((lane & 7) ^ (lane >> 3));   // pre-swizzled source slot
    const u16* Ag = A + (size_t)(row0 + srow) * K + scol;
    const u16* Bg = B + (size_t)(col0 + srow) * K + scol;

    for (int k0 = 0; k0 < K; k0 += 64) {
        #pragma unroll
        for (int i = 0; i < 4; ++i) {
            gload16(Ag + (size_t)i * 8 * K + k0, &As[w * 2048 + i * 512]);
            gload16(Bg + (size_t)i * 8 * K + k0, &Bs[w * 2048 + i * 512]);
        }
        __syncthreads();
        #pragma unroll
        for (int kk = 0; kk < 64; kk += 32) {
            int sl = (kk >> 3);   // 0 or 4
            bf16x8 af[4], bfr[4];
            #pragma unroll
            for (int mf = 0; mf < 4; ++mf)
                af[mf] = *reinterpret_cast<const bf16x8*>(
                    &As[(wm * 64 + mf * 16 + lr) * 64 + 8 * ((sl + lg) ^ lr7)]);
            #pragma unroll
            for (int nf = 0; nf < 4; ++nf)
                bfr[nf] = *reinterpret_cast<const bf16x8*>(
                    &Bs[(wn * 64 + nf * 16 + lr) * 64 + 8 * ((sl + lg) ^ lr7)]);
            #pragma unroll
            for (int mf = 0; mf < 4; ++mf)
                #pragma unroll
                for (int nf = 0; nf < 4; ++nf)
                    acc[mf][nf] = __builtin_amdgcn_mfma_f32_16x16x32_bf16(af[mf], bfr[nf], acc[mf][nf], 0, 0, 0);
        }
        __syncthreads();
    }

    int a_idx = (mode >= 0) ? mode : (col0 < 1024 ? 0 : (col0 < 1280 ? 1 : 2));
    float alpha = alpha_p[a_idx];
    #pragma unroll
    for (int mf = 0; mf < 4; ++mf) {
        #pragma unroll
        for (int reg = 0; reg < 4; ++reg) {
            int row = row0 + wm * 64 + mf * 16 + lg * 4 + reg;
            float sc = gamma[row] * alpha;
            #pragma unroll
            for (int nf = 0; nf < 4; ++nf)
                C[(size_t)row * cols + col0 + wn * 64 + nf * 16 + lr] = acc[mf][nf][reg] * sc;
        }
    }
}

// ---------------- rope table ----------------
__global__ __launch_bounds__(256) void k_rope(float* __restrict__ c, float* __restrict__ s) {
    int idx = blockIdx.x * 256 + threadIdx.x;  // < 32768
    int t = idx >> 5, i = idx & 31;
    float inv = 1.0f / powf(10000.0f, (float)(2 * i) * (1.0f / 64.0f));
    float f = (float)t * inv;
    c[idx] = cosf(f);
    s[idx] = sinf(f);
}

// ---------------- q prep: rms_norm + rope + gain (+score scale folded) -> bf16 ----------------
__global__ __launch_bounds__(256) void k_prep_q(const float* __restrict__ C,
                                                const float* __restrict__ rc,
                                                const float* __restrict__ rs,
                                                const float* __restrict__ gain,
                                                u16* __restrict__ Qo) {
    int lane = threadIdx.x & 63;
    int task = blockIdx.x * 4 + (threadIdx.x >> 6);  // (b*16+h)*1024+s
    int s = task & 1023;
    int h = (task >> 10) & 15;
    int b = task >> 14;
    float xv = C[((size_t)b * 1024 + s) * 1536 + h * 64 + lane];
    float ss = xv * xv;
    #pragma unroll
    for (int off = 32; off; off >>= 1) ss += __shfl_xor(ss, off);
    float r = 1.0f / sqrtf(ss * (1.0f / 64.0f) + 1.1920929e-07f);
    xv *= r;
    float xp = __shfl_xor(xv, 32);
    int i = lane & 31;
    float c = rc[s * 32 + i], sn = rs[s * 32 + i];
    float y = (lane < 32) ? (xv * c + xp * sn) : (xv * c - xp * sn);
    y *= gain[h] * (0.125f * 1.4426950408889634f);   // fold scale*log2(e) into Q
    Qo[(size_t)task * 64 + lane] = f2bf(y);
}

// ---------------- k prep (reads fused QKV gemm output, stride 1536, K at +1024) ----------------
__global__ __launch_bounds__(256) void k_prep_k(const float* __restrict__ C,
                                                const float* __restrict__ rc,
                                                const float* __restrict__ rs,
                                                u16* __restrict__ Ko) {
    int lane = threadIdx.x & 63;
    int task = blockIdx.x * 4 + (threadIdx.x >> 6);  // (b*4+kv)*1024+s
    int s = task & 1023;
    int kv = (task >> 10) & 3;
    int b = task >> 12;
    float xv = C[((size_t)b * 1024 + s) * 1536 + 1024 + kv * 64 + lane];
    float ss = xv * xv;
    #pragma unroll
    for (int off = 32; off; off >>= 1) ss += __shfl_xor(ss, off);
    float r = 1.0f / sqrtf(ss * (1.0f / 64.0f) + 1.1920929e-07f);
    xv *= r;
    float xp = __shfl_xor(xv, 32);
    int i = lane & 31;
    float c = rc[s * 32 + i], sn = rs[s * 32 + i];
    float y = (lane < 32) ? (xv * c + xp * sn) : (xv * c - xp * sn);
    Ko[(size_t)task * 64 + lane] = f2bf(y);
}

// ---------------- v transpose: C (stride 1536, V at +1280) -> Vt [b,kv,d,pos] bf16 ----------------
// key pos within each 64-block is INTERLEAVED: pos(s) = 2*(s&15) + ((s>>4)&1) + 32*(s>>5)
// (matches the attention P-store packing; P.V is invariant under the shared permutation)
__global__ __launch_bounds__(256) void k_vtransT(const float* __restrict__ C,
                                                 u16* __restrict__ Vt) {
    __shared__ u16 T[64][72];
    int st = blockIdx.x, kv = blockIdx.y, b = blockIdx.z;
    int tid = threadIdx.x;
    int sr = tid >> 4, d4 = tid & 15;
    #pragma unroll
    for (int i = 0; i < 4; ++i) {
        int s = sr + 16 * i;
        int pos = 2 * sr + (i & 1) + 32 * (i >> 1);
        float4 v = *reinterpret_cast<const float4*>(
            &C[(size_t)(b * 1024 + st * 64 + s) * 1536 + 1280 + kv * 64 + d4 * 4]);
        T[d4 * 4 + 0][pos] = f2bf(v.x);
        T[d4 * 4 + 1][pos] = f2bf(v.y);
        T[d4 * 4 + 2][pos] = f2bf(v.z);
        T[d4 * 4 + 3][pos] = f2bf(v.w);
    }
    __syncthreads();
    int d = tid >> 2, c = tid & 3;
    float4 o0 = *reinterpret_cast<const float4*>(&T[d][c * 16]);
    float4 o1 = *reinterpret_cast<const float4*>(&T[d][c * 16 + 8]);
    u16* out = &Vt[(((size_t)(b * 4 + kv) * 64) + d) * 1024 + st * 64 + c * 16];
    *reinterpret_cast<float4*>(out) = o0;
    *reinterpret_cast<float4*>(out + 8) = o1;
}

// ---------------- causal flash attention, bf16 MFMA, paired q-tiles ----------------
// grid (8,16,8), LDS = 40960 B exactly -> 4 blocks/CU. Defer-max + deferred denominator.
// P packed to bf16 pairs via v_cvt_pk_bf16_f32 into XOR-swizzled Ps strip (b32 writes).
__global__ __launch_bounds__(256, 4) void k_attn_mfma(const u16* __restrict__ Q,
                                                      const u16* __restrict__ K,
                                                      const u16* __restrict__ Vt,
                                                      float* __restrict__ Y) {
    __shared__ __align__(16) u16 KVs[2][2][4096];   // [buf][K/V][64*64], swizzled
    __shared__ __align__(16) u16 Ps[4][1024];       // per-wave P strip [16 q][64 pos], swizzled
    int qta = blockIdx.x, qtb = 15 - qta;
    int h = blockIdx.y, b = blockIdx.z;
    int kvh = h >> 2;
    int tid = threadIdx.x;
    int w = tid >> 6, lane = tid & 63;
    int lr = lane & 15, lg = lane >> 4;
    int lr7 = lr & 7;
    int q0a = qta * 64 + w * 16, q0b = qtb * 64 + w * 16;
    const u16* Qb = Q + (((size_t)b * 16 + h) * 1024) * 64;
    const u16* Kb = K + (((size_t)b * 4 + kvh) * 1024) * 64;
    const u16* Vb = Vt + (((size_t)b * 4 + kvh) * 64) * 1024;
    u16* Psw = Ps[w];
    unsigned* Pw32 = reinterpret_cast<unsigned*>(Psw);

    bf16x8 qa0 = *reinterpret_cast<const bf16x8*>(&Qb[(size_t)(q0a + lr) * 64 + 8 * lg]);
    bf16x8 qa1 = *reinterpret_cast<const bf16x8*>(&Qb[(size_t)(q0a + lr) * 64 + 32 + 8 * lg]);
    bf16x8 qb0 = *reinterpret_cast<const bf16x8*>(&Qb[(size_t)(q0b + lr) * 64 + 8 * lg]);
    bf16x8 qb1 = *reinterpret_cast<const bf16x8*>(&Qb[(size_t)(q0b + lr) * 64 + 32 + 8 * lg]);

    float mA[4], lpA[4], mB[4], lpB[4];   // lp = per-lane denominator partial
    f32x4 accA[4], accB[4];
    #pragma unroll
    for (int r = 0; r < 4; ++r) { mA[r] = -INFINITY; lpA[r] = 0.f; mB[r] = -INFINITY; lpB[r] = 0.f; }
    #pragma unroll
    for (int dt = 0; dt < 4; ++dt) { accA[dt] = (f32x4){0.f,0.f,0.f,0.f}; accB[dt] = (f32x4){0.f,0.f,0.f,0.f}; }

    int sub = lane >> 3, s7 = lane & 7;
    int scol16 = s7 ^ sub;
    int c0 = 2 * w, c1 = 2 * w + 1;

    #define STAGE(buf, t_) do { \
        int kk0 = (t_) * 64; \
        gload16(Kb + (size_t)(kk0 + 8 * c0 + sub) * 64 + scol16 * 8, &KVs[buf][0][c0 * 512]); \
        gload16(Kb + (size_t)(kk0 + 8 * c1 + sub) * 64 + scol16 * 8, &KVs[buf][0][c1 * 512]); \
        gload16(Vb + (size_t)(8 * c0 + sub) * 1024 + kk0 + scol16 * 8, &KVs[buf][1][c0 * 512]); \
        gload16(Vb + (size_t)(8 * c1 + sub) * 1024 + kk0 + scol16 * 8, &KVs[buf][1][c1 * 512]); \
    } while (0)

    STAGE(0, 0);
    asm volatile("s_waitcnt vmcnt(0)" ::: "memory");
    __syncthreads();
    int cur = 0;

    for (int t = 0; t <= qtb; ++t) {
        if (t < qtb) STAGE(cur ^ 1, t + 1);
        const int k0 = t * 64;
        const bool doA = (t <= qta);
        const u16* Kl = KVs[cur][0];
        const u16* Vl = KVs[cur][1];

        // ---- QK^T for both tiles (K-frags shared) ----
        float svA[4][4], svB[4][4];
        #pragma unroll
        for (int t4 = 0; t4 < 4; ++t4) {
            int r = t4 * 16 + lr;
            bf16x8 kf0 = *reinterpret_cast<const bf16x8*>(&Kl[r * 64 + ((lg ^ lr7) << 3)]);
            bf16x8 kf1 = *reinterpret_cast<const bf16x8*>(&Kl[r * 64 + (((4 | lg) ^ lr7) << 3)]);
            if (doA) {
                f32x4 z = (f32x4){0.f,0.f,0.f,0.f};
                z = __builtin_amdgcn_mfma_f32_16x16x32_bf16(qa0, kf0, z, 0, 0, 0);
                z = __builtin_amdgcn_mfma_f32_16x16x32_bf16(qa1, kf1, z, 0, 0, 0);
                #pragma unroll
                for (int rr = 0; rr < 4; ++rr) svA[t4][rr] = z[rr];
            }
            f32x4 z2 = (f32x4){0.f,0.f,0.f,0.f};
            z2 = __builtin_amdgcn_mfma_f32_16x16x32_bf16(qb0, kf0, z2, 0, 0, 0);
            z2 = __builtin_amdgcn_mfma_f32_16x16x32_bf16(qb1, kf1, z2, 0, 0, 0);
            #pragma unroll
            for (int rr = 0; rr < 4; ++rr) svB[t4][rr] = z2[rr];
        }
        if (doA && t == qta) {
            #pragma unroll
            for (int t4 = 0; t4 < 4; ++t4) {
                int key = k0 + t4 * 16 + lr;
                #pragma unroll
                for (int rr = 0; rr < 4; ++rr)
                    if (key > q0a + lg * 4 + rr) svA[t4][rr] = -3.0e38f;
            }
        }
        if (t == qtb) {
            #pragma unroll
            for (int t4 = 0; t4 < 4; ++t4) {
                int key = k0 + t4 * 16 + lr;
                #pragma unroll
                for (int rr = 0; rr < 4; ++rr)
                    if (key > q0b + lg * 4 + rr) svB[t4][rr] = -3.0e38f;
            }
        }

        // ---- softmax A (defer-max, packed P store) ----
        bf16x8 paA0, paA1, paB0, paB1;
        if (doA) {
            float vx[4]; int ok = 1;
            #pragma unroll
            for (int rr = 0; rr < 4; ++rr) {
                vx[rr] = fmaxf(fmaxf(svA[0][rr], svA[1][rr]), fmaxf(svA[2][rr], svA[3][rr]));
                ok &= (vx[rr] <= mA[rr] + 8.0f);
            }
            if (!__all(ok)) {
                #pragma unroll
                for (int rr = 0; rr < 4; ++rr) {
                    float mm = vx[rr];
                    #pragma unroll
                    for (int off = 8; off; off >>= 1) mm = fmaxf(mm, __shfl_xor(mm, off));
                    float mn = fmaxf(mA[rr], mm);
                    float corr = exp2f(mA[rr] - mn);
                    mA[rr] = mn;
                    lpA[rr] *= corr;
                    #pragma unroll
                    for (int dt = 0; dt < 4; ++dt) accA[dt][rr] *= corr;
                }
            }
            #pragma unroll
            for (int rr = 0; rr < 4; ++rr) {
                float p0 = exp2f(svA[0][rr] - mA[rr]);
                float p1 = exp2f(svA[1][rr] - mA[rr]);
                float p2 = exp2f(svA[2][rr] - mA[rr]);
                float p3 = exp2f(svA[3][rr] - mA[rr]);
                lpA[rr] += (p0 + p1) + (p2 + p3);
                unsigned pk01, pk23;
                asm("v_cvt_pk_bf16_f32 %0, %1, %2" : "=v"(pk01) : "v"(p0), "v"(p1));
                asm("v_cvt_pk_bf16_f32 %0, %1, %2" : "=v"(pk23) : "v"(p2), "v"(p3));
                int row = lg * 4 + rr, r7 = row & 7;
                Pw32[row * 32 + (((lr >> 2) ^ r7) << 2) + (lr & 3)] = pk01;
                Pw32[row * 32 + ((((lr >> 2) + 4) ^ r7) << 2) + (lr & 3)] = pk23;
            }
            paA0 = *reinterpret_cast<const bf16x8*>(&Psw[lr * 64 + ((lg ^ lr7) << 3)]);
            paA1 = *reinterpret_cast<const bf16x8*>(&Psw[lr * 64 + (((4 | lg) ^ lr7) << 3)]);
        }

        // ---- softmax B (defer-max, packed P store) ----
        {
            float vx[4]; int ok = 1;
            #pragma unroll
            for (int rr = 0; rr < 4; ++rr) {
                vx[rr] = fmaxf(fmaxf(svB[0][rr], svB[1][rr]), fmaxf(svB[2][rr], svB[3][rr]));
                ok &= (vx[rr] <= mB[rr] + 8.0f);
            }
            if (!__all(ok)) {
                #pragma unroll
                for (int rr = 0; rr < 4; ++rr) {
                    float mm = vx[rr];
                    #pragma unroll
                    for (int off = 8; off; off >>= 1) mm = fmaxf(mm, __shfl_xor(mm, off));
                    float mn = fmaxf(mB[rr], mm);
                    float corr = exp2f(mB[rr] - mn);
                    mB[rr] = mn;
                    lpB[rr] *= corr;
                    #pragma unroll
                    for (int dt = 0; dt < 4; ++dt) accB[dt][rr] *= corr;
                }
            }
            #pragma unroll
            for (int rr = 0; rr < 4; ++rr) {
                float p0 = exp2f(svB[0][rr] - mB[rr]);
                float p1 = exp2f(svB[1][rr] - mB[rr]);
                float p2 = exp2f(svB[2][rr] - mB[rr]);
                float p3 = exp2f(svB[3][rr] - mB[rr]);
                lpB[rr] += (p0 + p1) + (p2 + p3);
                unsigned pk01, pk23;
                asm("v_cvt_pk_bf16_f32 %0, %1, %2" : "=v"(pk01) : "v"(p0), "v"(p1));
                asm("v_cvt_pk_bf16_f32 %0, %1, %2" : "=v"(pk23) : "v"(p2), "v"(p3));
                int row = lg * 4 + rr, r7 = row & 7;
                Pw32[row * 32 + (((lr >> 2) ^ r7) << 2) + (lr & 3)] = pk01;
                Pw32[row * 32 + ((((lr >> 2) + 4) ^ r7) << 2) + (lr & 3)] = pk23;
            }
            paB0 = *reinterpret_cast<const bf16x8*>(&Psw[lr * 64 + ((lg ^ lr7) << 3)]);
            paB1 = *reinterpret_cast<const bf16x8*>(&Psw[lr * 64 + (((4 | lg) ^ lr7) << 3)]);
        }

        // ---- PV for both tiles (V-frags shared) ----
        #pragma unroll
        for (int dt = 0; dt < 4; ++dt) {
            int r = dt * 16 + lr;
            bf16x8 vf0 = *reinterpret_cast<const bf16x8*>(&Vl[r * 64 + ((lg ^ lr7) << 3)]);
            bf16x8 vf1 = *reinterpret_cast<const bf16x8*>(&Vl[r * 64 + (((4 | lg) ^ lr7) << 3)]);
            if (doA) {
                accA[dt] = __builtin_amdgcn_mfma_f32_16x16x32_bf16(paA0, vf0, accA[dt], 0, 0, 0);
                accA[dt] = __builtin_amdgcn_mfma_f32_16x16x32_bf16(paA1, vf1, accA[dt], 0, 0, 0);
            }
            accB[dt] = __builtin_amdgcn_mfma_f32_16x16x32_bf16(paB0, vf0, accB[dt], 0, 0, 0);
            accB[dt] = __builtin_amdgcn_mfma_f32_16x16x32_bf16(paB1, vf1, accB[dt], 0, 0, 0);
        }

        asm volatile("s_waitcnt vmcnt(0)" ::: "memory");
        __syncthreads();
        cur ^= 1;
    }
    #undef STAGE

    // final denominator reduce (deferred)
    #pragma unroll
    for (int rr = 0; rr < 4; ++rr) {
        #pragma unroll
        for (int off = 8; off; off >>= 1) {
            lpA[rr] += __shfl_xor(lpA[rr], off);
            lpB[rr] += __shfl_xor(lpB[rr], off);
        }
    }

    #pragma unroll
    for (int rr = 0; rr < 4; ++rr) {
        float invA = 1.0f / lpA[rr];
        float invB = 1.0f / lpB[rr];
        size_t baseA = ((size_t)(b * 1024 + q0a + lg * 4 + rr)) * 1024 + h * 64;
        size_t baseB = ((size_t)(b * 1024 + q0b + lg * 4 + rr)) * 1024 + h * 64;
        #pragma unroll
        for (int dt = 0; dt < 4; ++dt) {
            Y[baseA + dt * 16 + lr] = accA[dt][rr] * invA;
            Y[baseB + dt * 16 + lr] = accB[dt][rr] * invB;
        }
    }
}

extern "C" void kernel_launch(void* const* d_in, const int* in_sizes, int n_in,
                              void* d_out, int out_size, void* d_ws, size_t ws_size,
                              hipStream_t stream) {
    (void)in_sizes; (void)n_in; (void)out_size; (void)ws_size;
    const float* x  = (const float*)d_in[0];
    const float* Wq = (const float*)d_in[1];
    const float* Wk = (const float*)d_in[2];
    const float* Wv = (const float*)d_in[3];
    const float* Wp = (const float*)d_in[4];
    const float* qg = (const float*)d_in[5];
    float* out = (float*)d_out;

    float* p = (float*)d_ws;
    float* partial = p; p += 256;
    float* alpha = p;   p += 16;
    u16* wtqkv = (u16*)p; p += 786432;   // 1536x1024 u16 (Wq | Wk | Wv ternary)
    u16* wtp   = (u16*)p; p += 524288;   // 1024x1024 u16
    u16* xq    = (u16*)p; p += 4194304;  // 8192x1024 u16
    float* gam = p; p += 8192;
    float* cqkv = p; p += 12582912;      // f32 [8192][1536]
    u16* qo = (u16*)p; p += 4194304;     // bf16 [b,h,s,64]
    u16* ko = (u16*)p; p += 1048576;     // bf16 [b,kv,s,64]
    u16* vt = (u16*)p; p += 1048576;     // bf16 [b,kv,64,pos]
    float* rc = p; p += 32768;
    float* rs = p; p += 32768;
    float* y  = cqkv;      // reuse (cqkv dead after preps)
    u16*   yq = xq;        // reuse (xq dead after qkv gemm)

    // weight quantization
    k_absmean<<<64, 256, 0, stream>>>(Wq, 1048576, partial + 0);
    k_absmean<<<64, 256, 0, stream>>>(Wk, 262144, partial + 64);
    k_absmean<<<64, 256, 0, stream>>>(Wv, 262144, partial + 128);
    k_absmean<<<64, 256, 0, stream>>>(Wp, 1048576, partial + 192);
    k_alpha<<<1, 64, 0, stream>>>(partial, alpha);
    k_tern<<<512, 256, 0, stream>>>(Wq, alpha, 0, wtqkv, 262144);
    k_tern<<<128, 256, 0, stream>>>(Wk, alpha, 1, wtqkv + 1048576, 65536);
    k_tern<<<128, 256, 0, stream>>>(Wv, alpha, 2, wtqkv + 1310720, 65536);
    k_tern<<<512, 256, 0, stream>>>(Wp, alpha, 3, wtp, 262144);

    // rope table
    k_rope<<<128, 256, 0, stream>>>(rc, rs);

    // activation quantization + fused QKV projection (bf16 MFMA, exact integer math)
    k_quant<<<ROWS, 256, 0, stream>>>(x, xq, gam);
    k_gemm_mfma<<<dim3(12, 64), 256, 0, stream>>>(xq, wtqkv, gam, alpha, -1, cqkv, 1536);

    // norm + rope + layout
    k_prep_q<<<32768, 256, 0, stream>>>(cqkv, rc, rs, qg, qo);
    k_prep_k<<<8192, 256, 0, stream>>>(cqkv, rc, rs, ko);
    k_vtransT<<<dim3(16, 4, 8), 256, 0, stream>>>(cqkv, vt);

    // attention (bf16 MFMA flash, paired causal tiles, packed P, 4 blocks/CU)
    k_attn_mfma<<<dim3(8, 16, 8), 256, 0, stream>>>(qo, ko, vt, y);

    // output projection
    k_quant<<<ROWS, 256, 0, stream>>>(y, yq, gam);
    k_gemm_mfma<<<dim3(8, 64), 256, 0, stream>>>(yq, wtp, gam, alpha, 3, out, 1024);
}

// Round 7
// 261.675 us; speedup vs baseline: 1.3281x; 1.3281x over previous
//
#include <hip/hip_runtime.h>
#include <cmath>

#define DIMM 1024
#define NHEADS 16
#define NKV 4
#define HD 64
#define SEQ 1024
#define BSZ 8
#define ROWS (BSZ * SEQ)   // 8192

typedef unsigned short u16;
typedef __attribute__((ext_vector_type(8))) short bf16x8;
typedef __attribute__((ext_vector_type(4))) float f32x4;
typedef __attribute__((ext_vector_type(4))) unsigned short u16x4;

static __device__ __forceinline__ u16 f2bf(float f) {
    union { float f; unsigned u; } v; v.f = f;
    unsigned r = v.u + 0x7FFFu + ((v.u >> 16) & 1u);
    return (u16)(r >> 16);
}

// async global->LDS, 16B per lane; dst must be wave-uniform base (HW adds lane*16)
static __device__ __forceinline__ void gload16(const u16* g, u16* l) {
    __builtin_amdgcn_global_load_lds(
        (const __attribute__((address_space(1))) unsigned int*)g,
        (__attribute__((address_space(3))) unsigned int*)l, 16, 0, 0);
}

// ---------------- weight abs-mean partial reduce ----------------
__global__ __launch_bounds__(256) void k_absmean(const float* __restrict__ w, int n,
                                                 float* __restrict__ partial) {
    float s = 0.f;
    for (int i = blockIdx.x * 256 + threadIdx.x; i < n; i += 64 * 256) s += fabsf(w[i]);
    #pragma unroll
    for (int off = 32; off; off >>= 1) s += __shfl_xor(s, off);
    __shared__ float red[4];
    if ((threadIdx.x & 63) == 0) red[threadIdx.x >> 6] = s;
    __syncthreads();
    if (threadIdx.x == 0) partial[blockIdx.x] = red[0] + red[1] + red[2] + red[3];
}

// ---------------- alpha = max(mean|w|, eps) ----------------
__global__ void k_alpha(const float* __restrict__ partial, float* __restrict__ alpha) {
    int i = threadIdx.x;
    if (i < 4) {
        const int ns[4] = {1048576, 262144, 262144, 1048576};
        float s = 0.f;
        for (int j = 0; j < 64; ++j) s += partial[i * 64 + j];
        alpha[i] = fmaxf(s / (float)ns[i], 1e-8f);
    }
}

// ---------------- ternarize -> bf16 (values {-1,0,1}, exact) ----------------
__global__ __launch_bounds__(256) void k_tern(const float* __restrict__ w,
                                              const float* __restrict__ alpha, int ai,
                                              u16* __restrict__ wt, int n4) {
    float a = alpha[ai];
    for (int i = blockIdx.x * blockDim.x + threadIdx.x; i < n4; i += gridDim.x * blockDim.x) {
        float4 v = *reinterpret_cast<const float4*>(&w[i * 4]);
        u16x4 o;
        o.x = f2bf(rintf(fminf(fmaxf(v.x / a, -1.f), 1.f)));
        o.y = f2bf(rintf(fminf(fmaxf(v.y / a, -1.f), 1.f)));
        o.z = f2bf(rintf(fminf(fmaxf(v.z / a, -1.f), 1.f)));
        o.w = f2bf(rintf(fminf(fmaxf(v.w / a, -1.f), 1.f)));
        *reinterpret_cast<u16x4*>(&wt[i * 4]) = o;
    }
}

// ---------------- per-row activation quantization -> bf16 ints ----------------
__global__ __launch_bounds__(256) void k_quant(const float* __restrict__ X,
                                               u16* __restrict__ Xq, float* __restrict__ g) {
    int row = blockIdx.x;
    const float* xr = X + (size_t)row * DIMM;
    float4 v = *reinterpret_cast<const float4*>(&xr[threadIdx.x * 4]);
    float mv = fmaxf(fmaxf(fabsf(v.x), fabsf(v.y)), fmaxf(fabsf(v.z), fabsf(v.w)));
    #pragma unroll
    for (int off = 32; off; off >>= 1) mv = fmaxf(mv, __shfl_xor(mv, off));
    __shared__ float red[4];
    if ((threadIdx.x & 63) == 0) red[threadIdx.x >> 6] = mv;
    __syncthreads();
    mv = fmaxf(fmaxf(red[0], red[1]), fmaxf(red[2], red[3]));
    float gamma = fmaxf(mv, 1e-8f) / 127.0f;
    u16x4 o;
    o.x = f2bf(rintf(fminf(fmaxf(v.x / gamma, -128.f), 127.f)));
    o.y = f2bf(rintf(fminf(fmaxf(v.y / gamma, -128.f), 127.f)));
    o.z = f2bf(rintf(fminf(fmaxf(v.z / gamma, -128.f), 127.f)));
    o.w = f2bf(rintf(fminf(fmaxf(v.w / gamma, -128.f), 127.f)));
    *reinterpret_cast<u16x4*>(&Xq[(size_t)row * DIMM + threadIdx.x * 4]) = o;
    if (threadIdx.x == 0) g[row] = gamma;
}

// ---------------- bf16 MFMA GEMM (m97 structure + XOR-swizzled LDS) ----------------
// mode >= 0: C *= gamma[row]*alpha[mode].  mode < 0: fused QKV (cols 0..1023 -> alpha[0],
// 1024..1279 -> alpha[1], 1280..1535 -> alpha[2]).
__global__ __launch_bounds__(256) void k_gemm_mfma(const u16* __restrict__ A,
                                                   const u16* __restrict__ B,
                                                   const float* __restrict__ gamma,
                                                   const float* __restrict__ alpha_p, int mode,
                                                   float* __restrict__ C, int cols) {
    __shared__ u16 As[128 * 64];
    __shared__ u16 Bs[128 * 64];
    const int K = DIMM;
    int tid = threadIdx.x;
    int w = tid >> 6, lane = tid & 63;
    int lr = lane & 15, lg = lane >> 4;
    int lr7 = lr & 7;
    int wm = w >> 1, wn = w & 1;
    int row0 = blockIdx.y * 128, col0 = blockIdx.x * 128;

    f32x4 acc[4][4];
    #pragma unroll
    for (int mf = 0; mf < 4; ++mf)
        #pragma unroll
        for (int nf = 0; nf < 4; ++nf) acc[mf][nf] = (f32x4){0.f, 0.f, 0.f, 0.f};

    int srow = w * 32 + (lane >> 3);
    int scol = 8 * ((lane & 7) ^ (lane >> 3));   // pre-swizzled source slot
    const u16* Ag = A + (size_t)(row0 + srow) * K + scol;
    const u16* Bg = B + (size_t)(col0 + srow) * K + scol;

    for (int k0 = 0; k0 < K; k0 += 64) {
        #pragma unroll
        for (int i = 0; i < 4; ++i) {
            gload16(Ag + (size_t)i * 8 * K + k0, &As[w * 2048 + i * 512]);
            gload16(Bg + (size_t)i * 8 * K + k0, &Bs[w * 2048 + i * 512]);
        }
        __syncthreads();
        #pragma unroll
        for (int kk = 0; kk < 64; kk += 32) {
            int sl = (kk >> 3);   // 0 or 4
            bf16x8 af[4], bfr[4];
            #pragma unroll
            for (int mf = 0; mf < 4; ++mf)
                af[mf] = *reinterpret_cast<const bf16x8*>(
                    &As[(wm * 64 + mf * 16 + lr) * 64 + 8 * ((sl + lg) ^ lr7)]);
            #pragma unroll
            for (int nf = 0; nf < 4; ++nf)
                bfr[nf] = *reinterpret_cast<const bf16x8*>(
                    &Bs[(wn * 64 + nf * 16 + lr) * 64 + 8 * ((sl + lg) ^ lr7)]);
            #pragma unroll
            for (int mf = 0; mf < 4; ++mf)
                #pragma unroll
                for (int nf = 0; nf < 4; ++nf)
                    acc[mf][nf] = __builtin_amdgcn_mfma_f32_16x16x32_bf16(af[mf], bfr[nf], acc[mf][nf], 0, 0, 0);
        }
        __syncthreads();
    }

    int a_idx = (mode >= 0) ? mode : (col0 < 1024 ? 0 : (col0 < 1280 ? 1 : 2));
    float alpha = alpha_p[a_idx];
    #pragma unroll
    for (int mf = 0; mf < 4; ++mf) {
        #pragma unroll
        for (int reg = 0; reg < 4; ++reg) {
            int row = row0 + wm * 64 + mf * 16 + lg * 4 + reg;
            float sc = gamma[row] * alpha;
            #pragma unroll
            for (int nf = 0; nf < 4; ++nf)
                C[(size_t)row * cols + col0 + wn * 64 + nf * 16 + lr] = acc[mf][nf][reg] * sc;
        }
    }
}

// ---------------- rope table ----------------
__global__ __launch_bounds__(256) void k_rope(float* __restrict__ c, float* __restrict__ s) {
    int idx = blockIdx.x * 256 + threadIdx.x;  // < 32768
    int t = idx >> 5, i = idx & 31;
    float inv = 1.0f / powf(10000.0f, (float)(2 * i) * (1.0f / 64.0f));
    float f = (float)t * inv;
    c[idx] = cosf(f);
    s[idx] = sinf(f);
}

// ---------------- q prep: rms_norm + rope + gain (+score scale folded) -> bf16 ----------------
__global__ __launch_bounds__(256) void k_prep_q(const float* __restrict__ C,
                                                const float* __restrict__ rc,
                                                const float* __restrict__ rs,
                                                const float* __restrict__ gain,
                                                u16* __restrict__ Qo) {
    int lane = threadIdx.x & 63;
    int task = blockIdx.x * 4 + (threadIdx.x >> 6);  // (b*16+h)*1024+s
    int s = task & 1023;
    int h = (task >> 10) & 15;
    int b = task >> 14;
    float xv = C[((size_t)b * 1024 + s) * 1536 + h * 64 + lane];
    float ss = xv * xv;
    #pragma unroll
    for (int off = 32; off; off >>= 1) ss += __shfl_xor(ss, off);
    float r = 1.0f / sqrtf(ss * (1.0f / 64.0f) + 1.1920929e-07f);
    xv *= r;
    float xp = __shfl_xor(xv, 32);
    int i = lane & 31;
    float c = rc[s * 32 + i], sn = rs[s * 32 + i];
    float y = (lane < 32) ? (xv * c + xp * sn) : (xv * c - xp * sn);
    y *= gain[h] * (0.125f * 1.4426950408889634f);   // fold scale*log2(e) into Q
    Qo[(size_t)task * 64 + lane] = f2bf(y);
}

// ---------------- k prep (reads fused QKV gemm output, stride 1536, K at +1024) ----------------
__global__ __launch_bounds__(256) void k_prep_k(const float* __restrict__ C,
                                                const float* __restrict__ rc,
                                                const float* __restrict__ rs,
                                                u16* __restrict__ Ko) {
    int lane = threadIdx.x & 63;
    int task = blockIdx.x * 4 + (threadIdx.x >> 6);  // (b*4+kv)*1024+s
    int s = task & 1023;
    int kv = (task >> 10) & 3;
    int b = task >> 12;
    float xv = C[((size_t)b * 1024 + s) * 1536 + 1024 + kv * 64 + lane];
    float ss = xv * xv;
    #pragma unroll
    for (int off = 32; off; off >>= 1) ss += __shfl_xor(ss, off);
    float r = 1.0f / sqrtf(ss * (1.0f / 64.0f) + 1.1920929e-07f);
    xv *= r;
    float xp = __shfl_xor(xv, 32);
    int i = lane & 31;
    float c = rc[s * 32 + i], sn = rs[s * 32 + i];
    float y = (lane < 32) ? (xv * c + xp * sn) : (xv * c - xp * sn);
    Ko[(size_t)task * 64 + lane] = f2bf(y);
}

// ---------------- v transpose: C (stride 1536, V at +1280) -> Vt [b,kv,d,pos] bf16 ----------------
// key pos within each 64-block is INTERLEAVED: pos(s) = 2*(s&15) + ((s>>4)&1) + 32*(s>>5)
// (matches the attention P-store packing; P.V is invariant under the shared permutation)
__global__ __launch_bounds__(256) void k_vtransT(const float* __restrict__ C,
                                                 u16* __restrict__ Vt) {
    __shared__ u16 T[64][72];
    int st = blockIdx.x, kv = blockIdx.y, b = blockIdx.z;
    int tid = threadIdx.x;
    int sr = tid >> 4, d4 = tid & 15;
    #pragma unroll
    for (int i = 0; i < 4; ++i) {
        int s = sr + 16 * i;
        int pos = 2 * sr + (i & 1) + 32 * (i >> 1);
        float4 v = *reinterpret_cast<const float4*>(
            &C[(size_t)(b * 1024 + st * 64 + s) * 1536 + 1280 + kv * 64 + d4 * 4]);
        T[d4 * 4 + 0][pos] = f2bf(v.x);
        T[d4 * 4 + 1][pos] = f2bf(v.y);
        T[d4 * 4 + 2][pos] = f2bf(v.z);
        T[d4 * 4 + 3][pos] = f2bf(v.w);
    }
    __syncthreads();
    int d = tid >> 2, c = tid & 3;
    float4 o0 = *reinterpret_cast<const float4*>(&T[d][c * 16]);
    float4 o1 = *reinterpret_cast<const float4*>(&T[d][c * 16 + 8]);
    u16* out = &Vt[(((size_t)(b * 4 + kv) * 64) + d) * 1024 + st * 64 + c * 16];
    *reinterpret_cast<float4*>(out) = o0;
    *reinterpret_cast<float4*>(out + 8) = o1;
}

// ---------------- causal flash attention, bf16 MFMA, paired q-tiles ----------------
// grid (8,16,8), LDS = 40960 B. Plain launch_bounds(256): natural VGPR ~120 -> no spill
// (round-6 lesson: forcing min-waves clamps VGPR to 64 and spills, 10x HBM traffic).
__global__ __launch_bounds__(256) void k_attn_mfma(const u16* __restrict__ Q,
                                                   const u16* __restrict__ K,
                                                   const u16* __restrict__ Vt,
                                                   float* __restrict__ Y) {
    __shared__ __align__(16) u16 KVs[2][2][4096];   // [buf][K/V][64*64], swizzled
    __shared__ __align__(16) u16 Ps[4][1024];       // per-wave P strip [16 q][64 pos], swizzled
    int qta = blockIdx.x, qtb = 15 - qta;
    int h = blockIdx.y, b = blockIdx.z;
    int kvh = h >> 2;
    int tid = threadIdx.x;
    int w = tid >> 6, lane = tid & 63;
    int lr = lane & 15, lg = lane >> 4;
    int lr7 = lr & 7;
    int q0a = qta * 64 + w * 16, q0b = qtb * 64 + w * 16;
    const u16* Qb = Q + (((size_t)b * 16 + h) * 1024) * 64;
    const u16* Kb = K + (((size_t)b * 4 + kvh) * 1024) * 64;
    const u16* Vb = Vt + (((size_t)b * 4 + kvh) * 64) * 1024;
    u16* Psw = Ps[w];
    unsigned* Pw32 = reinterpret_cast<unsigned*>(Psw);

    bf16x8 qa0 = *reinterpret_cast<const bf16x8*>(&Qb[(size_t)(q0a + lr) * 64 + 8 * lg]);
    bf16x8 qa1 = *reinterpret_cast<const bf16x8*>(&Qb[(size_t)(q0a + lr) * 64 + 32 + 8 * lg]);
    bf16x8 qb0 = *reinterpret_cast<const bf16x8*>(&Qb[(size_t)(q0b + lr) * 64 + 8 * lg]);
    bf16x8 qb1 = *reinterpret_cast<const bf16x8*>(&Qb[(size_t)(q0b + lr) * 64 + 32 + 8 * lg]);

    float mA[4], lpA[4], mB[4], lpB[4];   // lp = per-lane denominator partial
    f32x4 accA[4], accB[4];
    #pragma unroll
    for (int r = 0; r < 4; ++r) { mA[r] = -INFINITY; lpA[r] = 0.f; mB[r] = -INFINITY; lpB[r] = 0.f; }
    #pragma unroll
    for (int dt = 0; dt < 4; ++dt) { accA[dt] = (f32x4){0.f,0.f,0.f,0.f}; accB[dt] = (f32x4){0.f,0.f,0.f,0.f}; }

    int sub = lane >> 3, s7 = lane & 7;
    int scol16 = s7 ^ sub;
    int c0 = 2 * w, c1 = 2 * w + 1;

    #define STAGE(buf, t_) do { \
        int kk0 = (t_) * 64; \
        gload16(Kb + (size_t)(kk0 + 8 * c0 + sub) * 64 + scol16 * 8, &KVs[buf][0][c0 * 512]); \
        gload16(Kb + (size_t)(kk0 + 8 * c1 + sub) * 64 + scol16 * 8, &KVs[buf][0][c1 * 512]); \
        gload16(Vb + (size_t)(8 * c0 + sub) * 1024 + kk0 + scol16 * 8, &KVs[buf][1][c0 * 512]); \
        gload16(Vb + (size_t)(8 * c1 + sub) * 1024 + kk0 + scol16 * 8, &KVs[buf][1][c1 * 512]); \
    } while (0)

    STAGE(0, 0);
    asm volatile("s_waitcnt vmcnt(0)" ::: "memory");
    __syncthreads();
    int cur = 0;

    for (int t = 0; t <= qtb; ++t) {
        if (t < qtb) STAGE(cur ^ 1, t + 1);
        const int k0 = t * 64;
        const bool doA = (t <= qta);
        const u16* Kl = KVs[cur][0];
        const u16* Vl = KVs[cur][1];

        // ---- QK^T for both tiles (K-frags shared) ----
        float svA[4][4], svB[4][4];
        #pragma unroll
        for (int t4 = 0; t4 < 4; ++t4) {
            int r = t4 * 16 + lr;
            bf16x8 kf0 = *reinterpret_cast<const bf16x8*>(&Kl[r * 64 + ((lg ^ lr7) << 3)]);
            bf16x8 kf1 = *reinterpret_cast<const bf16x8*>(&Kl[r * 64 + (((4 | lg) ^ lr7) << 3)]);
            if (doA) {
                f32x4 z = (f32x4){0.f,0.f,0.f,0.f};
                z = __builtin_amdgcn_mfma_f32_16x16x32_bf16(qa0, kf0, z, 0, 0, 0);
                z = __builtin_amdgcn_mfma_f32_16x16x32_bf16(qa1, kf1, z, 0, 0, 0);
                #pragma unroll
                for (int rr = 0; rr < 4; ++rr) svA[t4][rr] = z[rr];
            }
            f32x4 z2 = (f32x4){0.f,0.f,0.f,0.f};
            z2 = __builtin_amdgcn_mfma_f32_16x16x32_bf16(qb0, kf0, z2, 0, 0, 0);
            z2 = __builtin_amdgcn_mfma_f32_16x16x32_bf16(qb1, kf1, z2, 0, 0, 0);
            #pragma unroll
            for (int rr = 0; rr < 4; ++rr) svB[t4][rr] = z2[rr];
        }
        if (doA && t == qta) {
            #pragma unroll
            for (int t4 = 0; t4 < 4; ++t4) {
                int key = k0 + t4 * 16 + lr;
                #pragma unroll
                for (int rr = 0; rr < 4; ++rr)
                    if (key > q0a + lg * 4 + rr) svA[t4][rr] = -3.0e38f;
            }
        }
        if (t == qtb) {
            #pragma unroll
            for (int t4 = 0; t4 < 4; ++t4) {
                int key = k0 + t4 * 16 + lr;
                #pragma unroll
                for (int rr = 0; rr < 4; ++rr)
                    if (key > q0b + lg * 4 + rr) svB[t4][rr] = -3.0e38f;
            }
        }

        // ---- softmax A (defer-max, packed P store) ----
        bf16x8 paA0, paA1, paB0, paB1;
        if (doA) {
            float vx[4]; int ok = 1;
            #pragma unroll
            for (int rr = 0; rr < 4; ++rr) {
                vx[rr] = fmaxf(fmaxf(svA[0][rr], svA[1][rr]), fmaxf(svA[2][rr], svA[3][rr]));
                ok &= (vx[rr] <= mA[rr] + 8.0f);
            }
            if (!__all(ok)) {
                #pragma unroll
                for (int rr = 0; rr < 4; ++rr) {
                    float mm = vx[rr];
                    #pragma unroll
                    for (int off = 8; off; off >>= 1) mm = fmaxf(mm, __shfl_xor(mm, off));
                    float mn = fmaxf(mA[rr], mm);
                    float corr = exp2f(mA[rr] - mn);
                    mA[rr] = mn;
                    lpA[rr] *= corr;
                    #pragma unroll
                    for (int dt = 0; dt < 4; ++dt) accA[dt][rr] *= corr;
                }
            }
            #pragma unroll
            for (int rr = 0; rr < 4; ++rr) {
                float p0 = exp2f(svA[0][rr] - mA[rr]);
                float p1 = exp2f(svA[1][rr] - mA[rr]);
                float p2 = exp2f(svA[2][rr] - mA[rr]);
                float p3 = exp2f(svA[3][rr] - mA[rr]);
                lpA[rr] += (p0 + p1) + (p2 + p3);
                unsigned pk01, pk23;
                asm("v_cvt_pk_bf16_f32 %0, %1, %2" : "=v"(pk01) : "v"(p0), "v"(p1));
                asm("v_cvt_pk_bf16_f32 %0, %1, %2" : "=v"(pk23) : "v"(p2), "v"(p3));
                int row = lg * 4 + rr, r7 = row & 7;
                Pw32[row * 32 + (((lr >> 2) ^ r7) << 2) + (lr & 3)] = pk01;
                Pw32[row * 32 + ((((lr >> 2) + 4) ^ r7) << 2) + (lr & 3)] = pk23;
            }
            paA0 = *reinterpret_cast<const bf16x8*>(&Psw[lr * 64 + ((lg ^ lr7) << 3)]);
            paA1 = *reinterpret_cast<const bf16x8*>(&Psw[lr * 64 + (((4 | lg) ^ lr7) << 3)]);
        }

        // ---- softmax B (defer-max, packed P store) ----
        {
            float vx[4]; int ok = 1;
            #pragma unroll
            for (int rr = 0; rr < 4; ++rr) {
                vx[rr] = fmaxf(fmaxf(svB[0][rr], svB[1][rr]), fmaxf(svB[2][rr], svB[3][rr]));
                ok &= (vx[rr] <= mB[rr] + 8.0f);
            }
            if (!__all(ok)) {
                #pragma unroll
                for (int rr = 0; rr < 4; ++rr) {
                    float mm = vx[rr];
                    #pragma unroll
                    for (int off = 8; off; off >>= 1) mm = fmaxf(mm, __shfl_xor(mm, off));
                    float mn = fmaxf(mB[rr], mm);
                    float corr = exp2f(mB[rr] - mn);
                    mB[rr] = mn;
                    lpB[rr] *= corr;
                    #pragma unroll
                    for (int dt = 0; dt < 4; ++dt) accB[dt][rr] *= corr;
                }
            }
            #pragma unroll
            for (int rr = 0; rr < 4; ++rr) {
                float p0 = exp2f(svB[0][rr] - mB[rr]);
                float p1 = exp2f(svB[1][rr] - mB[rr]);
                float p2 = exp2f(svB[2][rr] - mB[rr]);
                float p3 = exp2f(svB[3][rr] - mB[rr]);
                lpB[rr] += (p0 + p1) + (p2 + p3);
                unsigned pk01, pk23;
                asm("v_cvt_pk_bf16_f32 %0, %1, %2" : "=v"(pk01) : "v"(p0), "v"(p1));
                asm("v_cvt_pk_bf16_f32 %0, %1, %2" : "=v"(pk23) : "v"(p2), "v"(p3));
                int row = lg * 4 + rr, r7 = row & 7;
                Pw32[row * 32 + (((lr >> 2) ^ r7) << 2) + (lr & 3)] = pk01;
                Pw32[row * 32 + ((((lr >> 2) + 4) ^ r7) << 2) + (lr & 3)] = pk23;
            }
            paB0 = *reinterpret_cast<const bf16x8*>(&Psw[lr * 64 + ((lg ^ lr7) << 3)]);
            paB1 = *reinterpret_cast<const bf16x8*>(&Psw[lr * 64 + (((4 | lg) ^ lr7) << 3)]);
        }

        // ---- PV for both tiles (V-frags shared) ----
        #pragma unroll
        for (int dt = 0; dt < 4; ++dt) {
            int r = dt * 16 + lr;
            bf16x8 vf0 = *reinterpret_cast<const bf16x8*>(&Vl[r * 64 + ((lg ^ lr7) << 3)]);
            bf16x8 vf1 = *reinterpret_cast<const bf16x8*>(&Vl[r * 64 + (((4 | lg) ^ lr7) << 3)]);
            if (doA) {
                accA[dt] = __builtin_amdgcn_mfma_f32_16x16x32_bf16(paA0, vf0, accA[dt], 0, 0, 0);
                accA[dt] = __builtin_amdgcn_mfma_f32_16x16x32_bf16(paA1, vf1, accA[dt], 0, 0, 0);
            }
            accB[dt] = __builtin_amdgcn_mfma_f32_16x16x32_bf16(paB0, vf0, accB[dt], 0, 0, 0);
            accB[dt] = __builtin_amdgcn_mfma_f32_16x16x32_bf16(paB1, vf1, accB[dt], 0, 0, 0);
        }

        asm volatile("s_waitcnt vmcnt(0)" ::: "memory");
        __syncthreads();
        cur ^= 1;
    }
    #undef STAGE

    // final denominator reduce (deferred)
    #pragma unroll
    for (int rr = 0; rr < 4; ++rr) {
        #pragma unroll
        for (int off = 8; off; off >>= 1) {
            lpA[rr] += __shfl_xor(lpA[rr], off);
            lpB[rr] += __shfl_xor(lpB[rr], off);
        }
    }

    #pragma unroll
    for (int rr = 0; rr < 4; ++rr) {
        float invA = 1.0f / lpA[rr];
        float invB = 1.0f / lpB[rr];
        size_t baseA = ((size_t)(b * 1024 + q0a + lg * 4 + rr)) * 1024 + h * 64;
        size_t baseB = ((size_t)(b * 1024 + q0b + lg * 4 + rr)) * 1024 + h * 64;
        #pragma unroll
        for (int dt = 0; dt < 4; ++dt) {
            Y[baseA + dt * 16 + lr] = accA[dt][rr] * invA;
            Y[baseB + dt * 16 + lr] = accB[dt][rr] * invB;
        }
    }
}

extern "C" void kernel_launch(void* const* d_in, const int* in_sizes, int n_in,
                              void* d_out, int out_size, void* d_ws, size_t ws_size,
                              hipStream_t stream) {
    (void)in_sizes; (void)n_in; (void)out_size; (void)ws_size;
    const float* x  = (const float*)d_in[0];
    const float* Wq = (const float*)d_in[1];
    const float* Wk = (const float*)d_in[2];
    const float* Wv = (const float*)d_in[3];
    const float* Wp = (const float*)d_in[4];
    const float* qg = (const float*)d_in[5];
    float* out = (float*)d_out;

    float* p = (float*)d_ws;
    float* partial = p; p += 256;
    float* alpha = p;   p += 16;
    u16* wtqkv = (u16*)p; p += 786432;   // 1536x1024 u16 (Wq | Wk | Wv ternary)
    u16* wtp   = (u16*)p; p += 524288;   // 1024x1024 u16
    u16* xq    = (u16*)p; p += 4194304;  // 8192x1024 u16
    float* gam = p; p += 8192;
    float* cqkv = p; p += 12582912;      // f32 [8192][1536]
    u16* qo = (u16*)p; p += 4194304;     // bf16 [b,h,s,64]
    u16* ko = (u16*)p; p += 1048576;     // bf16 [b,kv,s,64]
    u16* vt = (u16*)p; p += 1048576;     // bf16 [b,kv,64,pos]
    float* rc = p; p += 32768;
    float* rs = p; p += 32768;
    float* y  = cqkv;      // reuse (cqkv dead after preps)
    u16*   yq = xq;        // reuse (xq dead after qkv gemm)

    // weight quantization
    k_absmean<<<64, 256, 0, stream>>>(Wq, 1048576, partial + 0);
    k_absmean<<<64, 256, 0, stream>>>(Wk, 262144, partial + 64);
    k_absmean<<<64, 256, 0, stream>>>(Wv, 262144, partial + 128);
    k_absmean<<<64, 256, 0, stream>>>(Wp, 1048576, partial + 192);
    k_alpha<<<1, 64, 0, stream>>>(partial, alpha);
    k_tern<<<512, 256, 0, stream>>>(Wq, alpha, 0, wtqkv, 262144);
    k_tern<<<128, 256, 0, stream>>>(Wk, alpha, 1, wtqkv + 1048576, 65536);
    k_tern<<<128, 256, 0, stream>>>(Wv, alpha, 2, wtqkv + 1310720, 65536);
    k_tern<<<512, 256, 0, stream>>>(Wp, alpha, 3, wtp, 262144);

    // rope table
    k_rope<<<128, 256, 0, stream>>>(rc, rs);

    // activation quantization + fused QKV projection (bf16 MFMA, exact integer math)
    k_quant<<<ROWS, 256, 0, stream>>>(x, xq, gam);
    k_gemm_mfma<<<dim3(12, 64), 256, 0, stream>>>(xq, wtqkv, gam, alpha, -1, cqkv, 1536);

    // norm + rope + layout
    k_prep_q<<<32768, 256, 0, stream>>>(cqkv, rc, rs, qg, qo);
    k_prep_k<<<8192, 256, 0, stream>>>(cqkv, rc, rs, ko);
    k_vtransT<<<dim3(16, 4, 8), 256, 0, stream>>>(cqkv, vt);

    // attention (bf16 MFMA flash, paired causal tiles, packed P)
    k_attn_mfma<<<dim3(8, 16, 8), 256, 0, stream>>>(qo, ko, vt, y);

    // output projection
    k_quant<<<ROWS, 256, 0, stream>>>(y, yq, gam);
    k_gemm_mfma<<<dim3(8, 64), 256, 0, stream>>>(yq, wtp, gam, alpha, 3, out, 1024);
}